// Round 1
// baseline (1120.731 us; speedup 1.0000x reference)
//
#include <hip/hip_runtime.h>

#define B_SZ 2
#define LSEQ 2048
#define NH 24
#define DH 64
#define DS 128
#define DBLK 4              // d-blocks per (b,nh): each wg owns 16 d values
#define DPW (DH / DBLK)     // 16
#define SGN 16              // s-groups per d (16 lanes reduce together)
#define ES  8               // s-elements per thread (8 contiguous floats)
#define NT  (DPW * SGN)     // 256 threads

// One workgroup per (b, nh, dblk). Each thread holds h[d, s0..s0+7] in VGPRs.
// a_bar precomputed into LDS once per block (8 KB), hot loop is 2048 steps of
// 16 state-FMA + 8 y-FMA + 16-lane shfl_xor reduction, with depth-1 register
// prefetch of next step's B/C/x (addresses are state-independent).
__global__ __launch_bounds__(NT, 1)
void ssm_scan_kernel(const float* __restrict__ x, const float* __restrict__ A,
                     const float* __restrict__ Bm, const float* __restrict__ Cm,
                     const float* __restrict__ dp, float* __restrict__ y) {
    __shared__ float s_abar[LSEQ];

    const int blk  = blockIdx.x;
    const int dblk = blk % DBLK;
    const int bh   = blk / DBLK;      // b*NH + nh
    const int nh   = bh % NH;
    const int b    = bh / NH;

    // ---- precompute a_bar[t] for this (b, nh) into LDS ----
    const float dpv = dp[nh];
    for (int i = threadIdx.x; i < LSEQ; i += NT) {
        float a  = A[(b * LSEQ + i) * NH + nh];
        float z  = a + dpv;
        float sp = (z > 20.0f) ? z : log1pf(expf(z));   // softplus, stable
        s_abar[i] = expf(-sp * fabsf(a));
    }
    __syncthreads();

    const int tid  = threadIdx.x;
    const int dloc = tid >> 4;        // 0..15
    const int sg   = tid & 15;        // 0..15
    const int d    = dblk * DPW + dloc;
    const int sb   = sg * ES;

    const float4* __restrict__ bp =
        (const float4*)(Bm + ((size_t)(b * LSEQ) * NH + nh) * DS + sb);
    const float4* __restrict__ cp =
        (const float4*)(Cm + ((size_t)(b * LSEQ) * NH + nh) * DS + sb);
    const float* __restrict__ xp = x + ((size_t)(b * LSEQ) * NH + nh) * DH + d;
    float* __restrict__ yp       = y + ((size_t)(b * LSEQ) * NH + nh) * DH + d;

    const int BSTRIDE4 = NH * DS / 4;   // 768 float4 per step
    const int XSTRIDE  = NH * DH;       // 1536 floats per step

    float h0 = 0.f, h1 = 0.f, h2 = 0.f, h3 = 0.f;
    float h4 = 0.f, h5 = 0.f, h6 = 0.f, h7 = 0.f;

    // prefetch for t = 0
    float4 nb0 = bp[0], nb1 = bp[1];
    float4 nc0 = cp[0], nc1 = cp[1];
    float  nxv = xp[0];
    float  na  = s_abar[0];

    for (int t = 0; t < LSEQ; ++t) {
        const float4 B0 = nb0, B1 = nb1;
        const float4 C0 = nc0, C1 = nc1;
        const float  xd = nxv;
        const float  a  = na;

        // issue next step's loads (clamped at the end; no OOB)
        const int tn = (t + 1 < LSEQ) ? (t + 1) : t;
        {
            const float4* bpt = bp + (size_t)tn * BSTRIDE4;
            const float4* cpt = cp + (size_t)tn * BSTRIDE4;
            nb0 = bpt[0]; nb1 = bpt[1];
            nc0 = cpt[0]; nc1 = cpt[1];
            nxv = xp[(size_t)tn * XSTRIDE];
            na  = s_abar[tn];
        }

        // state update: h = a*h + xd*B
        h0 = fmaf(a, h0, xd * B0.x);
        h1 = fmaf(a, h1, xd * B0.y);
        h2 = fmaf(a, h2, xd * B0.z);
        h3 = fmaf(a, h3, xd * B0.w);
        h4 = fmaf(a, h4, xd * B1.x);
        h5 = fmaf(a, h5, xd * B1.y);
        h6 = fmaf(a, h6, xd * B1.z);
        h7 = fmaf(a, h7, xd * B1.w);

        // y partial: p = sum_j h[j]*C[j]  (two chains for ILP)
        float p0 = h0 * C0.x;
        p0 = fmaf(h1, C0.y, p0);
        p0 = fmaf(h2, C0.z, p0);
        p0 = fmaf(h3, C0.w, p0);
        float p1 = h4 * C1.x;
        p1 = fmaf(h5, C1.y, p1);
        p1 = fmaf(h6, C1.z, p1);
        p1 = fmaf(h7, C1.w, p1);
        float p = p0 + p1;

        // reduce over the 16 lanes (sg) sharing this d
        p += __shfl_xor(p, 1, 64);
        p += __shfl_xor(p, 2, 64);
        p += __shfl_xor(p, 4, 64);
        p += __shfl_xor(p, 8, 64);

        if (sg == 0) yp[(size_t)t * XSTRIDE] = p;
    }
}

extern "C" void kernel_launch(void* const* d_in, const int* in_sizes, int n_in,
                              void* d_out, int out_size, void* d_ws, size_t ws_size,
                              hipStream_t stream) {
    const float* x  = (const float*)d_in[0];
    const float* A  = (const float*)d_in[1];
    const float* Bm = (const float*)d_in[2];
    const float* Cm = (const float*)d_in[3];
    const float* dp = (const float*)d_in[4];
    float* y = (float*)d_out;

    dim3 grid(B_SZ * NH * DBLK);   // 192 workgroups
    dim3 block(NT);                // 256 threads
    hipLaunchKernelGGL(ssm_scan_kernel, grid, block, 0, stream,
                       x, A, Bm, Cm, dp, y);
}

// Round 2
// 684.905 us; speedup vs baseline: 1.6363x; 1.6363x over previous
//
#include <hip/hip_runtime.h>

#define B_SZ 2
#define LSEQ 2048
#define NH 24
#define DH 64
#define DS 128
#define DBLK 4              // d-blocks per (b,nh): each wg owns 16 d values
#define DPW (DH / DBLK)     // 16 d per wg
#define ES  8               // s-elements per thread
#define NT  256
#define TCH 32              // time-chunk staged in LDS
#define NCH (LSEQ / TCH)    // 64 chunks

// async global->LDS helpers (per-lane global addr, wave-uniform LDS base;
// HW writes lds_base + lane*size)
__device__ __forceinline__ void gload_lds16(const float* g, float* l) {
    __builtin_amdgcn_global_load_lds(
        (const __attribute__((address_space(1))) void*)g,
        (__attribute__((address_space(3))) void*)l, 16, 0, 0);
}
__device__ __forceinline__ void gload_lds4(const float* g, float* l) {
    __builtin_amdgcn_global_load_lds(
        (const __attribute__((address_space(1))) void*)g,
        (__attribute__((address_space(3))) void*)l, 4, 0, 0);
}

__global__ __launch_bounds__(NT, 1)
void ssm_scan_kernel(const float* __restrict__ x, const float* __restrict__ A,
                     const float* __restrict__ Bm, const float* __restrict__ Cm,
                     const float* __restrict__ dp, float* __restrict__ y) {
    __shared__ float s_abar[LSEQ];             // 8 KB
    __shared__ float s_B[2][TCH][DS];          // 32 KB
    __shared__ float s_C[2][TCH][DS];          // 32 KB
    __shared__ float s_x[2][TCH][DPW];         // 4 KB

    const int blk  = blockIdx.x;
    const int dblk = blk % DBLK;
    const int bh   = blk / DBLK;
    const int nh   = bh % NH;
    const int b    = bh / NH;

    // ---- precompute a_bar[t] for this (b, nh) into LDS ----
    const float dpv = dp[nh];
    for (int i = threadIdx.x; i < LSEQ; i += NT) {
        float a  = A[(b * LSEQ + i) * NH + nh];
        float z  = a + dpv;
        float sp = (z > 20.0f) ? z : log1pf(expf(z));
        s_abar[i] = expf(-sp * fabsf(a));
    }

    const int tid  = threadIdx.x;
    const int wid  = tid >> 6;        // wave 0..3
    const int lane = tid & 63;
    const int dloc = tid >> 4;        // 0..15
    const int sg   = tid & 15;        // 0..15
    const int sb   = sg * ES;

    const size_t bh_off = (size_t)(b * LSEQ) * NH + nh;   // row index base (t=0)
    const float* __restrict__ Bbase = Bm + bh_off * DS;
    const float* __restrict__ Cbase = Cm + bh_off * DS;
    const float* __restrict__ xbase = x + bh_off * DH + dblk * DPW;
    float* __restrict__ yp = y + bh_off * DH + dblk * DPW + dloc;

    const int RSTRIDE = NH * DS;      // floats per t in B/C
    const int XSTRIDE = NH * DH;      // floats per t in x/y

    // stage chunk starting at t0 into buffer `buf`
    auto stage = [&](int buf, int t0) {
        // B and C: 32 rows x 512B; each wave: 4 calls x (2 rows per call)
        #pragma unroll
        for (int j = 0; j < 4; ++j) {
            const int r0  = (wid * 4 + j) * 2;            // 0,2,..,30 (per wave)
            const int r   = r0 + (lane >> 5);             // this lane's row
            const int col = (lane & 31) * 4;              // this lane's 4 floats
            const float* gB = Bbase + (size_t)(t0 + r) * RSTRIDE + col;
            const float* gC = Cbase + (size_t)(t0 + r) * RSTRIDE + col;
            gload_lds16(gB, &s_B[buf][r0][0]);
            gload_lds16(gC, &s_C[buf][r0][0]);
        }
        // x slice: 32 rows x 16 floats = 512 elems; each wave: 2 calls x 64
        #pragma unroll
        for (int j = 0; j < 2; ++j) {
            const int idx = (wid * 2 + j) * 64 + lane;
            const int t   = idx >> 4;
            const int dc  = idx & 15;
            const float* gx = xbase + (size_t)(t0 + t) * XSTRIDE + dc;
            gload_lds4(gx, &s_x[buf][(wid * 2 + j) * 4][0]);
        }
    };

    stage(0, 0);
    __syncthreads();    // drains vmcnt(0): buffer 0 + s_abar ready

    float h0 = 0.f, h1 = 0.f, h2 = 0.f, h3 = 0.f;
    float h4 = 0.f, h5 = 0.f, h6 = 0.f, h7 = 0.f;

    for (int c = 0; c < NCH; ++c) {
        const int buf = c & 1;
        if (c + 1 < NCH) stage(buf ^ 1, (c + 1) * TCH);   // async into other buffer
        const int t0 = c * TCH;

        #pragma unroll 4
        for (int tt = 0; tt < TCH; ++tt) {
            const int t = t0 + tt;
            const float a  = s_abar[t];
            const float xd = s_x[buf][tt][dloc];
            const float4* Br = (const float4*)&s_B[buf][tt][sb];
            const float4* Cr = (const float4*)&s_C[buf][tt][sb];
            const float4 B0 = Br[0], B1 = Br[1];
            const float4 C0 = Cr[0], C1 = Cr[1];

            h0 = fmaf(a, h0, xd * B0.x);
            h1 = fmaf(a, h1, xd * B0.y);
            h2 = fmaf(a, h2, xd * B0.z);
            h3 = fmaf(a, h3, xd * B0.w);
            h4 = fmaf(a, h4, xd * B1.x);
            h5 = fmaf(a, h5, xd * B1.y);
            h6 = fmaf(a, h6, xd * B1.z);
            h7 = fmaf(a, h7, xd * B1.w);

            float p0 = h0 * C0.x;
            p0 = fmaf(h1, C0.y, p0);
            p0 = fmaf(h2, C0.z, p0);
            p0 = fmaf(h3, C0.w, p0);
            float p1 = h4 * C1.x;
            p1 = fmaf(h5, C1.y, p1);
            p1 = fmaf(h6, C1.z, p1);
            p1 = fmaf(h7, C1.w, p1);
            float p = p0 + p1;

            p += __shfl_xor(p, 1, 64);
            p += __shfl_xor(p, 2, 64);
            p += __shfl_xor(p, 4, 64);
            p += __shfl_xor(p, 8, 64);

            if (sg == 0) yp[(size_t)t * XSTRIDE] = p;
        }
        __syncthreads();   // drain staging of c+1, retire consumers of buf
    }
}

extern "C" void kernel_launch(void* const* d_in, const int* in_sizes, int n_in,
                              void* d_out, int out_size, void* d_ws, size_t ws_size,
                              hipStream_t stream) {
    const float* x  = (const float*)d_in[0];
    const float* A  = (const float*)d_in[1];
    const float* Bm = (const float*)d_in[2];
    const float* Cm = (const float*)d_in[3];
    const float* dp = (const float*)d_in[4];
    float* y = (float*)d_out;

    dim3 grid(B_SZ * NH * DBLK);   // 192 workgroups
    dim3 block(NT);
    hipLaunchKernelGGL(ssm_scan_kernel, grid, block, 0, stream,
                       x, A, Bm, Cm, dp, y);
}

// Round 3
// 286.400 us; speedup vs baseline: 3.9132x; 2.3914x over previous
//
#include <hip/hip_runtime.h>

#define B_SZ 2
#define LSEQ 2048
#define NHh 24
#define DHh 64
#define DSs 128
#define TCH 64                  // chunk length
#define NC  (LSEQ / TCH)        // 32 chunks
#define BH  (B_SZ * NHh)        // 48

// ws layout: S (fp32, 48*2048) | G (bf16, 48*32*128*64 [s][d]) | H (bf16 same)
#define S_ELEMS   (BH * LSEQ)
#define G_ELEMS   ((size_t)BH * NC * DSs * DHh)
#define WS_S_BYTES ((size_t)S_ELEMS * 4)
#define WS_G_BYTES (G_ELEMS * 2)
#define WS_REQ     (WS_S_BYTES + 2 * WS_G_BYTES)

__device__ __forceinline__ void gload_lds16(const float* g, void* l) {
    __builtin_amdgcn_global_load_lds(
        (const __attribute__((address_space(1))) void*)g,
        (__attribute__((address_space(3))) void*)l, 16, 0, 0);
}

__device__ __forceinline__ unsigned short f2bf(float f) {
    union { float f; unsigned u; } v; v.f = f;
    unsigned r = ((v.u >> 16) & 1u) + 0x7FFFu;
    return (unsigned short)((v.u + r) >> 16);
}
__device__ __forceinline__ float bf2f(unsigned short h) {
    union { unsigned u; float f; } v; v.u = ((unsigned)h) << 16; return v.f;
}

// ---------------- K1: per-chunk cumsum S + chunk contribution G ----------------
__global__ __launch_bounds__(256)
void k1_chunk(const float* __restrict__ x, const float* __restrict__ A,
              const float* __restrict__ Bm, const float* __restrict__ dp,
              float* __restrict__ S_ws, unsigned short* __restrict__ G_ws) {
    __shared__ float sX[TCH][DHh];     // 16 KB
    __shared__ float sB[TCH][DSs];     // 32 KB
    __shared__ float sF[TCH];

    const int c  = blockIdx.x & (NC - 1);
    const int bh = blockIdx.x >> 5;
    const int nh = bh % NHh;
    const int b  = bh / NHh;
    const int tid = threadIdx.x, w = tid >> 6, lane = tid & 63;

    const float* Bbase = Bm + ((size_t)(b * LSEQ + c * TCH) * NHh + nh) * DSs;
    const float* xbase = x  + ((size_t)(b * LSEQ + c * TCH) * NHh + nh) * DHh;

    #pragma unroll
    for (int j = 0; j < 8; ++j) {   // sB: 2 rows (128 fl) per call
        const int r0 = (w * 8 + j) * 2;
        gload_lds16(Bbase + (size_t)(r0 + (lane >> 5)) * (NHh * DSs) + (lane & 31) * 4,
                    &sB[r0][0]);
    }
    #pragma unroll
    for (int j = 0; j < 4; ++j) {   // sX: 4 rows (64 fl) per call
        const int r0 = (w * 4 + j) * 4;
        gload_lds16(xbase + (size_t)(r0 + (lane >> 4)) * (NHh * DHh) + (lane & 15) * 4,
                    &sX[r0][0]);
    }

    if (tid < 64) {   // wave0: log-decay cumsum
        float a  = A[(size_t)(b * LSEQ + c * TCH + tid) * NHh + nh];
        float z  = a + dp[nh];
        float sp = (z > 20.0f) ? z : log1pf(expf(z));
        float la = -sp * fabsf(a);
        #pragma unroll
        for (int off = 1; off < 64; off <<= 1) {
            float v = __shfl_up(la, off, 64);
            if (lane >= off) la += v;
        }
        S_ws[(size_t)bh * LSEQ + c * TCH + tid] = la;
        float s63 = __shfl(la, 63, 64);
        sF[tid] = expf(s63 - la);
    }
    __syncthreads();

    // G[s][d] = sum_u f_u * B_u[s] * x_u[d];  tile 4s x 8d per thread
    const int si = tid & 31, di = tid >> 5;
    const int s0 = si * 4, d0 = di * 8;
    float g[4][8];
    #pragma unroll
    for (int a1 = 0; a1 < 4; ++a1)
        #pragma unroll
        for (int a2 = 0; a2 < 8; ++a2) g[a1][a2] = 0.f;

    #pragma unroll 4
    for (int u = 0; u < TCH; ++u) {
        const float f = sF[u];
        const float4 bv = *(const float4*)&sB[u][s0];
        const float4 xa = *(const float4*)&sX[u][d0];
        const float4 xb = *(const float4*)&sX[u][d0 + 4];
        const float xv[8] = {xa.x, xa.y, xa.z, xa.w, xb.x, xb.y, xb.z, xb.w};
        const float fb[4] = {f * bv.x, f * bv.y, f * bv.z, f * bv.w};
        #pragma unroll
        for (int js = 0; js < 4; ++js)
            #pragma unroll
            for (int jd = 0; jd < 8; ++jd)
                g[js][jd] = fmaf(fb[js], xv[jd], g[js][jd]);
    }

    #pragma unroll
    for (int js = 0; js < 4; ++js) {
        uint4 p;
        p.x = (unsigned)f2bf(g[js][0]) | ((unsigned)f2bf(g[js][1]) << 16);
        p.y = (unsigned)f2bf(g[js][2]) | ((unsigned)f2bf(g[js][3]) << 16);
        p.z = (unsigned)f2bf(g[js][4]) | ((unsigned)f2bf(g[js][5]) << 16);
        p.w = (unsigned)f2bf(g[js][6]) | ((unsigned)f2bf(g[js][7]) << 16);
        size_t e = (((size_t)bh * NC + c) * DSs + (s0 + js)) * DHh + d0;
        *(uint4*)(G_ws + e) = p;
    }
}

// ---------------- K2: chunk-level scan, store chunk-entry states H ----------------
__global__ __launch_bounds__(256)
void k2_scan(const float* __restrict__ S_ws, const unsigned short* __restrict__ G_ws,
             unsigned short* __restrict__ H_ws) {
    const int dq = blockIdx.x & 3;
    const int bh = blockIdx.x >> 2;
    const int tid = threadIdx.x;
    const int s  = tid & 127;
    const int d0 = dq * 16 + (tid >> 7) * 8;

    float h[8];
    #pragma unroll
    for (int k = 0; k < 8; ++k) h[k] = 0.f;

    size_t base = (((size_t)bh * NC) * DSs + s) * DHh + d0;
    const size_t cstride = (size_t)DSs * DHh;

    uint4 gv = *(const uint4*)(G_ws + base);
    for (int c = 0; c < NC; ++c) {
        uint4 gn = (c + 1 < NC) ? *(const uint4*)(G_ws + base + (c + 1) * cstride) : gv;
        const float e = expf(S_ws[(size_t)bh * LSEQ + c * TCH + (TCH - 1)]);
        // store entry state
        uint4 p;
        p.x = (unsigned)f2bf(h[0]) | ((unsigned)f2bf(h[1]) << 16);
        p.y = (unsigned)f2bf(h[2]) | ((unsigned)f2bf(h[3]) << 16);
        p.z = (unsigned)f2bf(h[4]) | ((unsigned)f2bf(h[5]) << 16);
        p.w = (unsigned)f2bf(h[6]) | ((unsigned)f2bf(h[7]) << 16);
        *(uint4*)(H_ws + base + c * cstride) = p;
        // h = e*h + G_c
        const unsigned gu[4] = {gv.x, gv.y, gv.z, gv.w};
        #pragma unroll
        for (int k = 0; k < 4; ++k) {
            h[2 * k]     = fmaf(e, h[2 * k],     bf2f((unsigned short)(gu[k] & 0xffff)));
            h[2 * k + 1] = fmaf(e, h[2 * k + 1], bf2f((unsigned short)(gu[k] >> 16)));
        }
        gv = gn;
    }
}

// ---------------- K3: intra-chunk attention + inter-chunk term ----------------
__global__ __launch_bounds__(256)
void k3_y(const float* __restrict__ x, const float* __restrict__ Bm,
          const float* __restrict__ Cm, const float* __restrict__ S_ws,
          const unsigned short* __restrict__ H_ws, float* __restrict__ y) {
    __shared__ float sX[TCH][DHh];          // 16 KB
    __shared__ float sBT[DSs][TCH];         // 32 KB  B^T[k][u]
    __shared__ float sCT[DSs][TCH];         // 32 KB  C^T[k][t]
    __shared__ unsigned short sHT[DSs][DHh];// 16 KB  H[s][d] bf16
    __shared__ float sWT[TCH][TCH + 4];     // 17 KB  W^T[u][t], pad 4
    __shared__ float sS[TCH], sEt[TCH];

    const int c  = blockIdx.x & (NC - 1);
    const int bh = blockIdx.x >> 5;
    const int nh = bh % NHh;
    const int b  = bh / NHh;
    const int tid = threadIdx.x, w = tid >> 6, lane = tid & 63;

    // stage sX (row-major, async)
    const float* xbase = x + ((size_t)(b * LSEQ + c * TCH) * NHh + nh) * DHh;
    #pragma unroll
    for (int j = 0; j < 4; ++j) {
        const int r0 = (w * 4 + j) * 4;
        gload_lds16(xbase + (size_t)(r0 + (lane >> 4)) * (NHh * DHh) + (lane & 15) * 4,
                    &sX[r0][0]);
    }
    // stage sHT (contiguous bf16 chunk, async)
    {
        const unsigned short* Hbase = H_ws + ((size_t)bh * NC + c) * DSs * DHh;
        #pragma unroll
        for (int j = 0; j < 4; ++j) {
            const int off = (w * 4 + j) * 512;   // elems (= 1024 B)
            gload_lds16((const float*)(Hbase + off + lane * 8),
                        ((char*)&sHT[0][0]) + off * 2);
        }
    }
    // stage transposed B,C
    {
        const int t = tid & 63, kq = tid >> 6;
        const float* Crow = Cm + ((size_t)(b * LSEQ + c * TCH + t) * NHh + nh) * DSs;
        const float* Brow = Bm + ((size_t)(b * LSEQ + c * TCH + t) * NHh + nh) * DSs;
        #pragma unroll
        for (int i = 0; i < 8; ++i) {
            const int k = kq * 32 + i * 4;
            float4 cv = *(const float4*)(Crow + k);
            float4 bv = *(const float4*)(Brow + k);
            sCT[k][t] = cv.x; sCT[k + 1][t] = cv.y; sCT[k + 2][t] = cv.z; sCT[k + 3][t] = cv.w;
            sBT[k][t] = bv.x; sBT[k + 1][t] = bv.y; sBT[k + 2][t] = bv.z; sBT[k + 3][t] = bv.w;
        }
    }
    if (tid < 64) {
        float sv = S_ws[(size_t)bh * LSEQ + c * TCH + tid];
        sS[tid] = sv;
        sEt[tid] = expf(sv);
    }
    __syncthreads();

    // W phase: tile 4t x 4u; W[t,u] = exp(S_t-S_u) * dot_k(C_t, B_u), u<=t
    {
        const int ui = tid & 15, ti = tid >> 4;
        const int t0 = ti * 4, u0 = ui * 4;
        float wacc[4][4];
        #pragma unroll
        for (int a1 = 0; a1 < 4; ++a1)
            #pragma unroll
            for (int a2 = 0; a2 < 4; ++a2) wacc[a1][a2] = 0.f;
        #pragma unroll 8
        for (int k = 0; k < DSs; ++k) {
            const float4 cv = *(const float4*)&sCT[k][t0];
            const float4 bv = *(const float4*)&sBT[k][u0];
            const float cs[4] = {cv.x, cv.y, cv.z, cv.w};
            const float bs[4] = {bv.x, bv.y, bv.z, bv.w};
            #pragma unroll
            for (int jt = 0; jt < 4; ++jt)
                #pragma unroll
                for (int ju = 0; ju < 4; ++ju)
                    wacc[jt][ju] = fmaf(cs[jt], bs[ju], wacc[jt][ju]);
        }
        float st[4], su[4];
        #pragma unroll
        for (int j = 0; j < 4; ++j) { st[j] = sS[t0 + j]; su[j] = sS[u0 + j]; }
        #pragma unroll
        for (int ju = 0; ju < 4; ++ju) {
            float4 out;
            float* o = (float*)&out;
            #pragma unroll
            for (int jt = 0; jt < 4; ++jt) {
                const int t = t0 + jt, u = u0 + ju;
                o[jt] = (u <= t) ? wacc[jt][ju] * expf(st[jt] - su[ju]) : 0.f;
            }
            *(float4*)&sWT[u0 + ju][t0] = out;
        }
    }
    __syncthreads();

    // Y phase: y[t,d] = sum_u W[t,u] X[u,d]  +  E_t * sum_s C_t[s] H[s,d]
    {
        const int di = tid & 15, ti = tid >> 4;
        const int t0 = ti * 4, d0 = di * 4;
        float accY[4][4], accI[4][4];
        #pragma unroll
        for (int a1 = 0; a1 < 4; ++a1)
            #pragma unroll
            for (int a2 = 0; a2 < 4; ++a2) { accY[a1][a2] = 0.f; accI[a1][a2] = 0.f; }

        #pragma unroll 8
        for (int u = 0; u < TCH; ++u) {
            const float4 wv = *(const float4*)&sWT[u][t0];
            const float4 xv = *(const float4*)&sX[u][d0];
            const float ws_[4] = {wv.x, wv.y, wv.z, wv.w};
            const float xs_[4] = {xv.x, xv.y, xv.z, xv.w};
            #pragma unroll
            for (int jt = 0; jt < 4; ++jt)
                #pragma unroll
                for (int jd = 0; jd < 4; ++jd)
                    accY[jt][jd] = fmaf(ws_[jt], xs_[jd], accY[jt][jd]);
        }
        #pragma unroll 8
        for (int s = 0; s < DSs; ++s) {
            const float4 cv = *(const float4*)&sCT[s][t0];
            const uint2 hv = *(const uint2*)&sHT[s][d0];
            const float cs[4] = {cv.x, cv.y, cv.z, cv.w};
            const float hs[4] = {bf2f((unsigned short)(hv.x & 0xffff)),
                                 bf2f((unsigned short)(hv.x >> 16)),
                                 bf2f((unsigned short)(hv.y & 0xffff)),
                                 bf2f((unsigned short)(hv.y >> 16))};
            #pragma unroll
            for (int jt = 0; jt < 4; ++jt)
                #pragma unroll
                for (int jd = 0; jd < 4; ++jd)
                    accI[jt][jd] = fmaf(cs[jt], hs[jd], accI[jt][jd]);
        }
        #pragma unroll
        for (int jt = 0; jt < 4; ++jt) {
            const int t = t0 + jt;
            const float e = sEt[t];
            float4 out;
            out.x = fmaf(e, accI[jt][0], accY[jt][0]);
            out.y = fmaf(e, accI[jt][1], accY[jt][1]);
            out.z = fmaf(e, accI[jt][2], accY[jt][2]);
            out.w = fmaf(e, accI[jt][3], accY[jt][3]);
            *(float4*)(y + ((size_t)(b * LSEQ + c * TCH + t) * NHh + nh) * DHh + d0) = out;
        }
    }
}

// ---------------- fallback (R2 kernel, used only if ws too small) ----------------
#define F_DBLK 4
#define F_DPW 16
#define F_TCH 32
#define F_NCH (LSEQ / F_TCH)
__device__ __forceinline__ void gload_lds4(const float* g, float* l) {
    __builtin_amdgcn_global_load_lds(
        (const __attribute__((address_space(1))) void*)g,
        (__attribute__((address_space(3))) void*)l, 4, 0, 0);
}
__global__ __launch_bounds__(256, 1)
void ssm_scan_fb(const float* __restrict__ x, const float* __restrict__ A,
                 const float* __restrict__ Bm, const float* __restrict__ Cm,
                 const float* __restrict__ dp, float* __restrict__ y) {
    __shared__ float s_abar[LSEQ];
    __shared__ float s_B[2][F_TCH][DSs];
    __shared__ float s_C[2][F_TCH][DSs];
    __shared__ float s_x[2][F_TCH][F_DPW];
    const int blk = blockIdx.x;
    const int dblk = blk % F_DBLK, bh = blk / F_DBLK;
    const int nh = bh % NHh, b = bh / NHh;
    const float dpv = dp[nh];
    for (int i = threadIdx.x; i < LSEQ; i += 256) {
        float a = A[(b * LSEQ + i) * NHh + nh];
        float z = a + dpv;
        float sp = (z > 20.0f) ? z : log1pf(expf(z));
        s_abar[i] = expf(-sp * fabsf(a));
    }
    const int tid = threadIdx.x, wid = tid >> 6, lane = tid & 63;
    const int dloc = tid >> 4, sg = tid & 15, sb = sg * 8;
    const size_t bh_off = (size_t)(b * LSEQ) * NHh + nh;
    const float* Bbase = Bm + bh_off * DSs;
    const float* Cbase = Cm + bh_off * DSs;
    const float* xbase = x + bh_off * DHh + dblk * F_DPW;
    float* yp = y + bh_off * DHh + dblk * F_DPW + dloc;
    const int RSTRIDE = NHh * DSs, XSTRIDE = NHh * DHh;
    auto stage = [&](int buf, int t0) {
        #pragma unroll
        for (int j = 0; j < 4; ++j) {
            const int r0 = (wid * 4 + j) * 2, r = r0 + (lane >> 5), col = (lane & 31) * 4;
            gload_lds16(Bbase + (size_t)(t0 + r) * RSTRIDE + col, &s_B[buf][r0][0]);
            gload_lds16(Cbase + (size_t)(t0 + r) * RSTRIDE + col, &s_C[buf][r0][0]);
        }
        #pragma unroll
        for (int j = 0; j < 2; ++j) {
            const int idx = (wid * 2 + j) * 64 + lane, t = idx >> 4, dc = idx & 15;
            gload_lds4(xbase + (size_t)(t0 + t) * XSTRIDE + dc, &s_x[buf][(wid * 2 + j) * 4][0]);
        }
    };
    stage(0, 0);
    __syncthreads();
    float h0=0,h1=0,h2=0,h3=0,h4=0,h5=0,h6=0,h7=0;
    for (int c = 0; c < F_NCH; ++c) {
        const int buf = c & 1;
        if (c + 1 < F_NCH) stage(buf ^ 1, (c + 1) * F_TCH);
        const int t0 = c * F_TCH;
        #pragma unroll 4
        for (int tt = 0; tt < F_TCH; ++tt) {
            const int t = t0 + tt;
            const float a = s_abar[t], xd = s_x[buf][tt][dloc];
            const float4* Br = (const float4*)&s_B[buf][tt][sb];
            const float4* Cr = (const float4*)&s_C[buf][tt][sb];
            const float4 B0 = Br[0], B1 = Br[1], C0 = Cr[0], C1 = Cr[1];
            h0 = fmaf(a, h0, xd * B0.x); h1 = fmaf(a, h1, xd * B0.y);
            h2 = fmaf(a, h2, xd * B0.z); h3 = fmaf(a, h3, xd * B0.w);
            h4 = fmaf(a, h4, xd * B1.x); h5 = fmaf(a, h5, xd * B1.y);
            h6 = fmaf(a, h6, xd * B1.z); h7 = fmaf(a, h7, xd * B1.w);
            float p0 = h0 * C0.x; p0 = fmaf(h1, C0.y, p0); p0 = fmaf(h2, C0.z, p0); p0 = fmaf(h3, C0.w, p0);
            float p1 = h4 * C1.x; p1 = fmaf(h5, C1.y, p1); p1 = fmaf(h6, C1.z, p1); p1 = fmaf(h7, C1.w, p1);
            float p = p0 + p1;
            p += __shfl_xor(p, 1, 64); p += __shfl_xor(p, 2, 64);
            p += __shfl_xor(p, 4, 64); p += __shfl_xor(p, 8, 64);
            if (sg == 0) yp[(size_t)t * XSTRIDE] = p;
        }
        __syncthreads();
    }
}

extern "C" void kernel_launch(void* const* d_in, const int* in_sizes, int n_in,
                              void* d_out, int out_size, void* d_ws, size_t ws_size,
                              hipStream_t stream) {
    const float* x  = (const float*)d_in[0];
    const float* A  = (const float*)d_in[1];
    const float* Bm = (const float*)d_in[2];
    const float* Cm = (const float*)d_in[3];
    const float* dp = (const float*)d_in[4];
    float* y = (float*)d_out;

    if (ws_size >= WS_REQ) {
        float* S_ws = (float*)d_ws;
        unsigned short* G_ws = (unsigned short*)((char*)d_ws + WS_S_BYTES);
        unsigned short* H_ws = G_ws + G_ELEMS;
        hipLaunchKernelGGL(k1_chunk, dim3(BH * NC), dim3(256), 0, stream,
                           x, A, Bm, dp, S_ws, G_ws);
        hipLaunchKernelGGL(k2_scan, dim3(BH * 4), dim3(256), 0, stream,
                           S_ws, G_ws, H_ws);
        hipLaunchKernelGGL(k3_y, dim3(BH * NC), dim3(256), 0, stream,
                           x, Bm, Cm, S_ws, H_ws, y);
    } else {
        hipLaunchKernelGGL(ssm_scan_fb, dim3(BH * F_DBLK), dim3(256), 0, stream,
                           x, A, Bm, Cm, dp, y);
    }
}

// Round 4
// 188.945 us; speedup vs baseline: 5.9315x; 1.5158x over previous
//
#include <hip/hip_runtime.h>

#define B_SZ 2
#define LSEQ 2048
#define NHh 24
#define DHh 64
#define DSs 128
#define TCH 64                  // chunk length
#define NC  (LSEQ / TCH)        // 32 chunks
#define BH  (B_SZ * NHh)        // 48

// ws layout: S (fp32) | G (bf16, [bh][c][d][s]) | H (bf16, same layout)
#define S_ELEMS   (BH * LSEQ)
#define G_ELEMS   ((size_t)BH * NC * DSs * DHh)
#define WS_S_BYTES ((size_t)S_ELEMS * 4)
#define WS_G_BYTES (G_ELEMS * 2)
#define WS_REQ     (WS_S_BYTES + 2 * WS_G_BYTES)

#define SP  136   // padded row length for k=128 (s) tiles: 272 B stride, 16B-aligned
#define UP  72    // padded row length for k=64  (u) tiles: 144 B stride, 16B-aligned

typedef __attribute__((ext_vector_type(8))) short bf16x8;
typedef __attribute__((ext_vector_type(4))) float f32x4;

__device__ __forceinline__ unsigned short f2bf(float f) {
    union { float f; unsigned u; } v; v.f = f;
    unsigned r = ((v.u >> 16) & 1u) + 0x7FFFu;
    return (unsigned short)((v.u + r) >> 16);
}
__device__ __forceinline__ float bf2f(unsigned short h) {
    union { unsigned u; float f; } v; v.u = ((unsigned)h) << 16; return v.f;
}
__device__ __forceinline__ unsigned pk2(float a, float b) {
    return (unsigned)f2bf(a) | ((unsigned)f2bf(b) << 16);
}

// ============ K1: cumsum S + G = (f*X)^T-major MFMA, G_ws in [d][s] ============
__global__ __launch_bounds__(256, 2)
void k1_chunk(const float* __restrict__ x, const float* __restrict__ A,
              const float* __restrict__ Bm, const float* __restrict__ dp,
              float* __restrict__ S_ws, unsigned short* __restrict__ G_ws) {
    __shared__ __align__(16) unsigned short sBT[DSs][UP];  // B^T [s][u]
    __shared__ __align__(16) unsigned short sXT[DHh][UP];  // (f*x)^T [d][u]
    __shared__ float sF[TCH];

    const int c  = blockIdx.x & (NC - 1);
    const int bh = blockIdx.x >> 5;
    const int nh = bh % NHh; const int b = bh / NHh;
    const int tid = threadIdx.x;
    const int lane = tid & 63;
    const int w = tid >> 6;

    const size_t row0 = (size_t)(b * LSEQ + c * TCH) * NHh + nh;

    // issue global loads into registers (row u = tid>>2, 4 lanes cover 64B chunks)
    const int u = tid >> 2;
    const int q = tid & 3;
    const float* Brow = Bm + (row0 + (size_t)u * NHh) * DSs;
    const float* xrow = x  + (row0 + (size_t)u * NHh) * DHh;
    float4 bv[8], xv[4];
    #pragma unroll
    for (int j = 0; j < 8; ++j) bv[j] = *(const float4*)(Brow + (j * 4 + q) * 4);
    #pragma unroll
    for (int j = 0; j < 4; ++j) xv[j] = *(const float4*)(xrow + (j * 4 + q) * 4);

    if (tid < 64) {   // wave0: log-decay cumsum
        float a  = A[row0 + (size_t)tid * NHh];
        float z  = a + dp[nh];
        float sp = (z > 20.0f) ? z : log1pf(expf(z));
        float la = -sp * fabsf(a);
        #pragma unroll
        for (int off = 1; off < 64; off <<= 1) {
            float v = __shfl_up(la, off, 64);
            if (lane >= off) la += v;
        }
        S_ws[(size_t)bh * LSEQ + c * TCH + tid] = la;
        float s63 = __shfl(la, 63, 64);
        sF[tid] = expf(s63 - la);
    }
    __syncthreads();

    // transpose-convert into LDS
    #pragma unroll
    for (int j = 0; j < 8; ++j) {
        const int s = (j * 4 + q) * 4;
        sBT[s + 0][u] = f2bf(bv[j].x);
        sBT[s + 1][u] = f2bf(bv[j].y);
        sBT[s + 2][u] = f2bf(bv[j].z);
        sBT[s + 3][u] = f2bf(bv[j].w);
    }
    const float f = sF[u];
    #pragma unroll
    for (int j = 0; j < 4; ++j) {
        const int d = (j * 4 + q) * 4;
        sXT[d + 0][u] = f2bf(xv[j].x * f);
        sXT[d + 1][u] = f2bf(xv[j].y * f);
        sXT[d + 2][u] = f2bf(xv[j].z * f);
        sXT[d + 3][u] = f2bf(xv[j].w * f);
    }
    __syncthreads();

    // MFMA: Gt[d][s] = sum_u XfT[d][u] * BT[s][u]; wave w owns d-rows [16w,16w+16)
    const int fr = lane >> 4, fc = lane & 15;
    bf16x8 afr0 = *(const bf16x8*)&sXT[16 * w + fc][fr * 8];
    bf16x8 afr1 = *(const bf16x8*)&sXT[16 * w + fc][32 + fr * 8];
    #pragma unroll
    for (int st = 0; st < 8; ++st) {
        f32x4 acc = {0.f, 0.f, 0.f, 0.f};
        bf16x8 b0 = *(const bf16x8*)&sBT[st * 16 + fc][fr * 8];
        bf16x8 b1 = *(const bf16x8*)&sBT[st * 16 + fc][32 + fr * 8];
        acc = __builtin_amdgcn_mfma_f32_16x16x32_bf16(afr0, b0, acc, 0, 0, 0);
        acc = __builtin_amdgcn_mfma_f32_16x16x32_bf16(afr1, b1, acc, 0, 0, 0);
        unsigned short* gout = G_ws +
            ((((size_t)bh * NC + c) * DHh + 16 * w + fr * 4) * DSs) + st * 16 + fc;
        #pragma unroll
        for (int r = 0; r < 4; ++r) gout[(size_t)r * DSs] = f2bf(acc[r]);
    }
}

// ============ K2: chunk-level scan over [d][s] planes ============
__global__ __launch_bounds__(256)
void k2_scan(const float* __restrict__ S_ws, const unsigned short* __restrict__ G_ws,
             unsigned short* __restrict__ H_ws) {
    const int dblk = blockIdx.x & 3;
    const int bh   = blockIdx.x >> 2;
    const int tid  = threadIdx.x;
    const int d    = dblk * 16 + (tid >> 4);
    const int s0   = (tid & 15) * 8;

    float h[8];
    #pragma unroll
    for (int k = 0; k < 8; ++k) h[k] = 0.f;

    size_t base = (((size_t)bh * NC) * DHh + d) * DSs + s0;
    const size_t cstride = (size_t)DHh * DSs;

    uint4 gv = *(const uint4*)(G_ws + base);
    for (int c = 0; c < NC; ++c) {
        uint4 gn = (c + 1 < NC) ? *(const uint4*)(G_ws + base + (size_t)(c + 1) * cstride) : gv;
        const float e = expf(S_ws[(size_t)bh * LSEQ + c * TCH + (TCH - 1)]);
        uint4 p;
        p.x = pk2(h[0], h[1]); p.y = pk2(h[2], h[3]);
        p.z = pk2(h[4], h[5]); p.w = pk2(h[6], h[7]);
        *(uint4*)(H_ws + base + (size_t)c * cstride) = p;
        const unsigned gu[4] = {gv.x, gv.y, gv.z, gv.w};
        #pragma unroll
        for (int k = 0; k < 4; ++k) {
            h[2 * k]     = fmaf(e, h[2 * k],     bf2f((unsigned short)(gu[k] & 0xffff)));
            h[2 * k + 1] = fmaf(e, h[2 * k + 1], bf2f((unsigned short)(gu[k] >> 16)));
        }
        gv = gn;
    }
}

// ============ K3: W = mask*exp o (C.B^T); y = W.X + E o (C.H^T), all MFMA ============
__global__ __launch_bounds__(256, 2)
void k3_y(const float* __restrict__ x, const float* __restrict__ Bm,
          const float* __restrict__ Cm, const float* __restrict__ S_ws,
          const unsigned short* __restrict__ H_ws, float* __restrict__ y) {
    __shared__ __align__(16) unsigned short sC[TCH][SP];   // C [t][s] bf16
    __shared__ __align__(16) unsigned short sB[TCH][SP];   // B [u][s] bf16
    __shared__ __align__(16) unsigned short sH[DHh][SP];   // H [d][s] bf16
    __shared__ __align__(16) unsigned short sW[TCH][UP];   // W [t][u] bf16
    __shared__ __align__(16) unsigned short sXT[DHh][UP];  // X^T [d][u] bf16
    __shared__ float sS[TCH];
    __shared__ float sEt[TCH];

    const int c  = blockIdx.x & (NC - 1);
    const int bh = blockIdx.x >> 5;
    const int nh = bh % NHh; const int b = bh / NHh;
    const int tid = threadIdx.x;
    const int lane = tid & 63;
    const int w = tid >> 6;

    const size_t row0 = (size_t)(b * LSEQ + c * TCH) * NHh + nh;

    // global loads to registers
    const int rr = tid >> 2;    // row (t for C/B/X; d for H)
    const int q  = tid & 3;
    const float* Crow = Cm + (row0 + (size_t)rr * NHh) * DSs;
    const float* Brow = Bm + (row0 + (size_t)rr * NHh) * DSs;
    const float* xrow = x  + (row0 + (size_t)rr * NHh) * DHh;
    const unsigned short* Hrow = H_ws + (((size_t)bh * NC + c) * DHh + rr) * DSs;
    float4 cv[8], bv[8], xv[4];
    uint4  hv[4];
    #pragma unroll
    for (int j = 0; j < 8; ++j) cv[j] = *(const float4*)(Crow + (j * 4 + q) * 4);
    #pragma unroll
    for (int j = 0; j < 8; ++j) bv[j] = *(const float4*)(Brow + (j * 4 + q) * 4);
    #pragma unroll
    for (int j = 0; j < 4; ++j) xv[j] = *(const float4*)(xrow + (j * 4 + q) * 4);
    #pragma unroll
    for (int j = 0; j < 4; ++j) hv[j] = *(const uint4*)(Hrow + (j * 4 + q) * 8);

    if (tid < 64) {
        float sv = S_ws[(size_t)bh * LSEQ + c * TCH + tid];
        sS[tid]  = sv;
        sEt[tid] = expf(sv);
    }

    // convert/write LDS
    #pragma unroll
    for (int j = 0; j < 8; ++j) {
        const int s = (j * 4 + q) * 4;
        *(uint2*)&sC[rr][s] = make_uint2(pk2(cv[j].x, cv[j].y), pk2(cv[j].z, cv[j].w));
        *(uint2*)&sB[rr][s] = make_uint2(pk2(bv[j].x, bv[j].y), pk2(bv[j].z, bv[j].w));
    }
    #pragma unroll
    for (int j = 0; j < 4; ++j)
        *(uint4*)&sH[rr][(j * 4 + q) * 8] = hv[j];
    #pragma unroll
    for (int j = 0; j < 4; ++j) {
        const int d = (j * 4 + q) * 4;
        sXT[d + 0][rr] = f2bf(xv[j].x);
        sXT[d + 1][rr] = f2bf(xv[j].y);
        sXT[d + 2][rr] = f2bf(xv[j].z);
        sXT[d + 3][rr] = f2bf(xv[j].w);
    }
    __syncthreads();

    const int fr = lane >> 4, fc = lane & 15;
    const int t0w = 16 * w;

    // ---- W phase: wave w owns t-rows [t0w, t0w+16) ----
    bf16x8 ca[4];
    #pragma unroll
    for (int kb = 0; kb < 4; ++kb)
        ca[kb] = *(const bf16x8*)&sC[t0w + fc][kb * 32 + fr * 8];
    float st4[4];
    #pragma unroll
    for (int r = 0; r < 4; ++r) st4[r] = sS[t0w + fr * 4 + r];

    #pragma unroll
    for (int ut = 0; ut < 4; ++ut) {
        const int u0 = ut * 16;
        unsigned short wv[4] = {0, 0, 0, 0};
        if (ut <= w) {   // tiles fully in the future are all-zero
            f32x4 acc = {0.f, 0.f, 0.f, 0.f};
            #pragma unroll
            for (int kb = 0; kb < 4; ++kb) {
                bf16x8 bb = *(const bf16x8*)&sB[u0 + fc][kb * 32 + fr * 8];
                acc = __builtin_amdgcn_mfma_f32_16x16x32_bf16(ca[kb], bb, acc, 0, 0, 0);
            }
            const float su = sS[u0 + fc];
            const int   uu = u0 + fc;
            #pragma unroll
            for (int r = 0; r < 4; ++r) {
                const int t = t0w + fr * 4 + r;
                const float dd = fminf(st4[r] - su, 0.f);
                const float val = (uu <= t) ? acc[r] * expf(dd) : 0.f;
                wv[r] = f2bf(val);
            }
        }
        #pragma unroll
        for (int r = 0; r < 4; ++r) sW[t0w + fr * 4 + r][u0 + fc] = wv[r];
    }
    // no __syncthreads: each wave reads only the sW rows it wrote (lgkmcnt ordering)

    // ---- Y phase: acc = C.H^T (K=128), scale by E_t, then += W.X (K=64) ----
    bf16x8 wa0 = *(const bf16x8*)&sW[t0w + fc][fr * 8];
    bf16x8 wa1;
    if (w >= 2) wa1 = *(const bf16x8*)&sW[t0w + fc][32 + fr * 8];
    float et4[4];
    #pragma unroll
    for (int r = 0; r < 4; ++r) et4[r] = sEt[t0w + fr * 4 + r];

    #pragma unroll
    for (int dt = 0; dt < 4; ++dt) {
        const int d0 = dt * 16;
        f32x4 acc = {0.f, 0.f, 0.f, 0.f};
        #pragma unroll
        for (int kb = 0; kb < 4; ++kb) {
            bf16x8 hb = *(const bf16x8*)&sH[d0 + fc][kb * 32 + fr * 8];
            acc = __builtin_amdgcn_mfma_f32_16x16x32_bf16(ca[kb], hb, acc, 0, 0, 0);
        }
        #pragma unroll
        for (int r = 0; r < 4; ++r) acc[r] *= et4[r];
        bf16x8 xb0 = *(const bf16x8*)&sXT[d0 + fc][fr * 8];
        acc = __builtin_amdgcn_mfma_f32_16x16x32_bf16(wa0, xb0, acc, 0, 0, 0);
        if (w >= 2) {
            bf16x8 xb1 = *(const bf16x8*)&sXT[d0 + fc][32 + fr * 8];
            acc = __builtin_amdgcn_mfma_f32_16x16x32_bf16(wa1, xb1, acc, 0, 0, 0);
        }
        float* yout = y + (row0 + (size_t)(t0w + fr * 4) * NHh) * DHh + d0 + fc;
        #pragma unroll
        for (int r = 0; r < 4; ++r) yout[(size_t)r * NHh * DHh] = acc[r];
    }
}

// ============ fallback (R2 kernel) ============
__device__ __forceinline__ void gload_lds16(const float* g, void* l) {
    __builtin_amdgcn_global_load_lds(
        (const __attribute__((address_space(1))) void*)g,
        (__attribute__((address_space(3))) void*)l, 16, 0, 0);
}
__device__ __forceinline__ void gload_lds4(const float* g, float* l) {
    __builtin_amdgcn_global_load_lds(
        (const __attribute__((address_space(1))) void*)g,
        (__attribute__((address_space(3))) void*)l, 4, 0, 0);
}
#define F_DBLK 4
#define F_DPW 16
#define F_TCH 32
#define F_NCH (LSEQ / F_TCH)
__global__ __launch_bounds__(256, 1)
void ssm_scan_fb(const float* __restrict__ x, const float* __restrict__ A,
                 const float* __restrict__ Bm, const float* __restrict__ Cm,
                 const float* __restrict__ dp, float* __restrict__ y) {
    __shared__ float s_abar[LSEQ];
    __shared__ float s_B[2][F_TCH][DSs];
    __shared__ float s_C[2][F_TCH][DSs];
    __shared__ float s_x[2][F_TCH][F_DPW];
    const int blk = blockIdx.x;
    const int dblk = blk % F_DBLK, bh = blk / F_DBLK;
    const int nh = bh % NHh, b = bh / NHh;
    const float dpv = dp[nh];
    for (int i = threadIdx.x; i < LSEQ; i += 256) {
        float a = A[(b * LSEQ + i) * NHh + nh];
        float z = a + dpv;
        float sp = (z > 20.0f) ? z : log1pf(expf(z));
        s_abar[i] = expf(-sp * fabsf(a));
    }
    const int tid = threadIdx.x, wid = tid >> 6, lane = tid & 63;
    const int dloc = tid >> 4, sg = tid & 15, sb = sg * 8;
    const size_t bh_off = (size_t)(b * LSEQ) * NHh + nh;
    const float* Bbase = Bm + bh_off * DSs;
    const float* Cbase = Cm + bh_off * DSs;
    const float* xbase = x + bh_off * DHh + dblk * F_DPW;
    float* yp = y + bh_off * DHh + dblk * F_DPW + dloc;
    const int RSTRIDE = NHh * DSs, XSTRIDE = NHh * DHh;
    auto stage = [&](int buf, int t0) {
        #pragma unroll
        for (int j = 0; j < 4; ++j) {
            const int r0 = (wid * 4 + j) * 2, r = r0 + (lane >> 5), col = (lane & 31) * 4;
            gload_lds16(Bbase + (size_t)(t0 + r) * RSTRIDE + col, &s_B[buf][r0][0]);
            gload_lds16(Cbase + (size_t)(t0 + r) * RSTRIDE + col, &s_C[buf][r0][0]);
        }
        #pragma unroll
        for (int j = 0; j < 2; ++j) {
            const int idx = (wid * 2 + j) * 64 + lane, t = idx >> 4, dc = idx & 15;
            gload_lds4(xbase + (size_t)(t0 + t) * XSTRIDE + dc, &s_x[buf][(wid * 2 + j) * 4][0]);
        }
    };
    stage(0, 0);
    __syncthreads();
    float h0=0,h1=0,h2=0,h3=0,h4=0,h5=0,h6=0,h7=0;
    for (int c = 0; c < F_NCH; ++c) {
        const int buf = c & 1;
        if (c + 1 < F_NCH) stage(buf ^ 1, (c + 1) * F_TCH);
        const int t0 = c * F_TCH;
        #pragma unroll 4
        for (int tt = 0; tt < F_TCH; ++tt) {
            const int t = t0 + tt;
            const float a = s_abar[t], xd = s_x[buf][tt][dloc];
            const float4* Br = (const float4*)&s_B[buf][tt][sb];
            const float4* Cr = (const float4*)&s_C[buf][tt][sb];
            const float4 B0 = Br[0], B1 = Br[1], C0 = Cr[0], C1 = Cr[1];
            h0 = fmaf(a, h0, xd * B0.x); h1 = fmaf(a, h1, xd * B0.y);
            h2 = fmaf(a, h2, xd * B0.z); h3 = fmaf(a, h3, xd * B0.w);
            h4 = fmaf(a, h4, xd * B1.x); h5 = fmaf(a, h5, xd * B1.y);
            h6 = fmaf(a, h6, xd * B1.z); h7 = fmaf(a, h7, xd * B1.w);
            float p0 = h0 * C0.x; p0 = fmaf(h1, C0.y, p0); p0 = fmaf(h2, C0.z, p0); p0 = fmaf(h3, C0.w, p0);
            float p1 = h4 * C1.x; p1 = fmaf(h5, C1.y, p1); p1 = fmaf(h6, C1.z, p1); p1 = fmaf(h7, C1.w, p1);
            float p = p0 + p1;
            p += __shfl_xor(p, 1, 64); p += __shfl_xor(p, 2, 64);
            p += __shfl_xor(p, 4, 64); p += __shfl_xor(p, 8, 64);
            if (sg == 0) yp[(size_t)t * XSTRIDE] = p;
        }
        __syncthreads();
    }
}

extern "C" void kernel_launch(void* const* d_in, const int* in_sizes, int n_in,
                              void* d_out, int out_size, void* d_ws, size_t ws_size,
                              hipStream_t stream) {
    const float* x  = (const float*)d_in[0];
    const float* A  = (const float*)d_in[1];
    const float* Bm = (const float*)d_in[2];
    const float* Cm = (const float*)d_in[3];
    const float* dp = (const float*)d_in[4];
    float* y = (float*)d_out;

    if (ws_size >= WS_REQ) {
        float* S_ws = (float*)d_ws;
        unsigned short* G_ws = (unsigned short*)((char*)d_ws + WS_S_BYTES);
        unsigned short* H_ws = G_ws + G_ELEMS;
        hipLaunchKernelGGL(k1_chunk, dim3(BH * NC), dim3(256), 0, stream,
                           x, A, Bm, dp, S_ws, G_ws);
        hipLaunchKernelGGL(k2_scan, dim3(BH * 4), dim3(256), 0, stream,
                           S_ws, G_ws, H_ws);
        hipLaunchKernelGGL(k3_y, dim3(BH * NC), dim3(256), 0, stream,
                           x, Bm, Cm, S_ws, H_ws, y);
    } else {
        hipLaunchKernelGGL(ssm_scan_fb, dim3(BH * F_DBLK), dim3(256), 0, stream,
                           x, A, Bm, Cm, dp, y);
    }
}